// Round 1
// baseline (135.767 us; speedup 1.0000x reference)
//
#include <hip/hip_runtime.h>
#include <hip/hip_bf16.h>
#include <math.h>

#define H 256
#define BQ 1024
#define NPOOL 32768
#define MAXN 64

// ---------------------------------------------------------------------------
// Kernel 1: q = relu(enc @ Wq + bq) * (1/sqrt(H)); one block per output row.
// Result written into d_out (later read-then-overwritten by attn kernel,
// same block touches same region only -> safe).
// ---------------------------------------------------------------------------
__global__ __launch_bounds__(256) void qproj_kernel(
    const float* __restrict__ enc, const float* __restrict__ Wq,
    const float* __restrict__ bq, float* __restrict__ qout) {
  __shared__ float x[H];
  const int row = blockIdx.x;
  const int tid = threadIdx.x;
  x[tid] = enc[row * H + tid];
  __syncthreads();
  float acc = bq[tid];
#pragma unroll 8
  for (int k = 0; k < H; ++k) acc = fmaf(x[k], Wq[k * H + tid], acc);
  acc = fmaxf(acc, 0.f);
  qout[row * H + tid] = acc * 0.0625f;  // 1/sqrt(256)
}

// ---------------------------------------------------------------------------
// Kernel 2: K = relu(soc @ Wk + bk), V = relu(soc @ Wv + bv).
// fp32 tiled GEMM: BM=64 x BN=64 per block, BK=16, 4x4 register blocking,
// both outputs per block (shared A tile).
// ---------------------------------------------------------------------------
__global__ __launch_bounds__(256) void kvproj_kernel(
    const float* __restrict__ soc,
    const float* __restrict__ Wk, const float* __restrict__ bk,
    const float* __restrict__ Wv, const float* __restrict__ bv,
    float* __restrict__ kout, float* __restrict__ vout) {
  constexpr int BM = 64, BN = 64, BK = 16;
  __shared__ __attribute__((aligned(16))) float As[BK][68];  // [k][row], padded
  __shared__ __attribute__((aligned(16))) float Bk[BK][68];  // [k][col]
  __shared__ __attribute__((aligned(16))) float Bv[BK][68];

  const int tid = threadIdx.x;
  const int row0 = blockIdx.x * BM;
  const int col0 = blockIdx.y * BN;
  const int tx = tid & 15, ty = tid >> 4;

  // loader mapping
  const int la_row = tid >> 2;         // 0..63
  const int la_k4 = (tid & 3) * 4;     // 0,4,8,12
  const int lb_k = tid >> 4;           // 0..15
  const int lb_c4 = (tid & 15) * 4;    // 0..60

  float accK[4][4] = {};
  float accV[4][4] = {};

  for (int k0 = 0; k0 < H; k0 += BK) {
    const float4 av =
        *(const float4*)(soc + (size_t)(row0 + la_row) * H + k0 + la_k4);
    As[la_k4 + 0][la_row] = av.x;
    As[la_k4 + 1][la_row] = av.y;
    As[la_k4 + 2][la_row] = av.z;
    As[la_k4 + 3][la_row] = av.w;
    *(float4*)(&Bk[lb_k][lb_c4]) =
        *(const float4*)(Wk + (size_t)(k0 + lb_k) * H + col0 + lb_c4);
    *(float4*)(&Bv[lb_k][lb_c4]) =
        *(const float4*)(Wv + (size_t)(k0 + lb_k) * H + col0 + lb_c4);
    __syncthreads();
#pragma unroll
    for (int kk = 0; kk < BK; ++kk) {
      const float4 a = *(const float4*)(&As[kk][ty * 4]);
      const float4 b0 = *(const float4*)(&Bk[kk][tx * 4]);
      const float4 b1 = *(const float4*)(&Bv[kk][tx * 4]);
      const float af[4] = {a.x, a.y, a.z, a.w};
      const float bkf[4] = {b0.x, b0.y, b0.z, b0.w};
      const float bvf[4] = {b1.x, b1.y, b1.z, b1.w};
#pragma unroll
      for (int i = 0; i < 4; ++i)
#pragma unroll
        for (int j = 0; j < 4; ++j) {
          accK[i][j] = fmaf(af[i], bkf[j], accK[i][j]);
          accV[i][j] = fmaf(af[i], bvf[j], accV[i][j]);
        }
    }
    __syncthreads();
  }

  // epilogue: bias + relu, vectorized stores
#pragma unroll
  for (int i = 0; i < 4; ++i) {
    const int r = row0 + ty * 4 + i;
    const int cb = col0 + tx * 4;
    float4 ko, vo;
    ko.x = fmaxf(accK[i][0] + bk[cb + 0], 0.f);
    ko.y = fmaxf(accK[i][1] + bk[cb + 1], 0.f);
    ko.z = fmaxf(accK[i][2] + bk[cb + 2], 0.f);
    ko.w = fmaxf(accK[i][3] + bk[cb + 3], 0.f);
    vo.x = fmaxf(accV[i][0] + bv[cb + 0], 0.f);
    vo.y = fmaxf(accV[i][1] + bv[cb + 1], 0.f);
    vo.z = fmaxf(accV[i][2] + bv[cb + 2], 0.f);
    vo.w = fmaxf(accV[i][3] + bv[cb + 3], 0.f);
    *(float4*)(kout + (size_t)r * H + cb) = ko;
    *(float4*)(vout + (size_t)r * H + cb) = vo;
  }
}

// ---------------------------------------------------------------------------
// Kernel 3: per-sample sliced attention. One block (4 waves) per sample.
// qbuf aliases out (read-before-write within the owning block only).
// ---------------------------------------------------------------------------
__global__ __launch_bounds__(256) void attn_kernel(
    const float* qbuf, const float* __restrict__ kbuf,
    const float* __restrict__ vbuf, const int* __restrict__ starts,
    const int* __restrict__ ends, float* out) {
  __shared__ float qs[H];
  __shared__ float sc[MAXN];
  const int row = blockIdx.x;
  const int tid = threadIdx.x;
  const int lane = tid & 63;
  const int wave = tid >> 6;
  const int start = starts[row];
  const int len = ends[row] - start;  // guaranteed 1..64

  qs[tid] = qbuf[row * H + tid];
  __syncthreads();

  // scores: wave w handles neighbors w, w+4, ...
  for (int j = wave; j < len; j += 4) {
    const float* krow = kbuf + (size_t)(start + j) * H;
    float s = 0.f;
#pragma unroll
    for (int e = 0; e < 4; ++e)
      s = fmaf(qs[lane + e * 64], krow[lane + e * 64], s);
#pragma unroll
    for (int off = 32; off > 0; off >>= 1) s += __shfl_down(s, off, 64);
    if (lane == 0) sc[j] = s;
  }
  __syncthreads();

  // softmax over len scores (first wave)
  if (tid < 64) {
    const float x = (tid < len) ? sc[tid] : -INFINITY;
    float m = x;
#pragma unroll
    for (int off = 32; off > 0; off >>= 1)
      m = fmaxf(m, __shfl_xor(m, off, 64));
    const float p = (tid < len) ? __expf(x - m) : 0.f;
    float ssum = p;
#pragma unroll
    for (int off = 32; off > 0; off >>= 1) ssum += __shfl_xor(ssum, off, 64);
    sc[tid] = p / ssum;
  }
  __syncthreads();

  // out = attn @ v ; one column per thread, coalesced v reads
  float acc = 0.f;
  for (int j = 0; j < len; ++j)
    acc = fmaf(sc[j], vbuf[(size_t)(start + j) * H + tid], acc);
  out[row * H + tid] = acc;
}

// ---------------------------------------------------------------------------
extern "C" void kernel_launch(void* const* d_in, const int* in_sizes, int n_in,
                              void* d_out, int out_size, void* d_ws,
                              size_t ws_size, hipStream_t stream) {
  (void)in_sizes; (void)n_in; (void)out_size; (void)ws_size;
  const float* enc = (const float*)d_in[0];
  const float* soc = (const float*)d_in[1];
  const int* starts = (const int*)d_in[2];
  const int* ends = (const int*)d_in[3];
  const float* Wq = (const float*)d_in[4];
  const float* bq = (const float*)d_in[5];
  const float* Wk = (const float*)d_in[6];
  const float* bk = (const float*)d_in[7];
  const float* Wv = (const float*)d_in[8];
  const float* bv = (const float*)d_in[9];
  float* out = (float*)d_out;

  float* kbuf = (float*)d_ws;                       // 32768*256 f32 = 32 MB
  float* vbuf = kbuf + (size_t)NPOOL * H;           // 32 MB

  qproj_kernel<<<BQ, 256, 0, stream>>>(enc, Wq, bq, out);
  kvproj_kernel<<<dim3(NPOOL / 64, H / 64), 256, 0, stream>>>(
      soc, Wk, bk, Wv, bv, kbuf, vbuf);
  attn_kernel<<<BQ, 256, 0, stream>>>(out, kbuf, vbuf, starts, ends, out);
}

// Round 2
// 67.556 us; speedup vs baseline: 2.0097x; 2.0097x over previous
//
#include <hip/hip_runtime.h>
#include <hip/hip_bf16.h>
#include <math.h>

#define H 256
#define BQ 1024
#define NPOOL 32768
#define MAXN 64

typedef __attribute__((ext_vector_type(8))) short short8;
typedef __attribute__((ext_vector_type(8))) unsigned short ushort8v;
typedef __attribute__((ext_vector_type(4))) float f32x4;

__device__ __forceinline__ unsigned short f2bf(float f) {
  unsigned int u = __float_as_uint(f);
  unsigned int r = (u + 0x7fffu + ((u >> 16) & 1u)) >> 16;
  return (unsigned short)r;
}
__device__ __forceinline__ float b2f(unsigned short u) {
  return __uint_as_float((unsigned int)u << 16);
}
__device__ __forceinline__ void gload16(const void* g, void* l) {
  __builtin_amdgcn_global_load_lds(
      (const __attribute__((address_space(1))) unsigned int*)g,
      (__attribute__((address_space(3))) unsigned int*)l, 16, 0, 0);
}

// ---------------------------------------------------------------------------
// convert soc fp32 -> bf16 (8 elems/thread)
// ---------------------------------------------------------------------------
__global__ __launch_bounds__(256) void convert_soc_kernel(
    const float* __restrict__ in, unsigned short* __restrict__ out) {
  const int i = blockIdx.x * 256 + threadIdx.x;
  const float4 a = *(const float4*)(in + (size_t)i * 8);
  const float4 b = *(const float4*)(in + (size_t)i * 8 + 4);
  ushort8v r;
  r[0] = f2bf(a.x); r[1] = f2bf(a.y); r[2] = f2bf(a.z); r[3] = f2bf(a.w);
  r[4] = f2bf(b.x); r[5] = f2bf(b.y); r[6] = f2bf(b.z); r[7] = f2bf(b.w);
  *(ushort8v*)(out + (size_t)i * 8) = r;
}

// ---------------------------------------------------------------------------
// transpose + convert Wk/Wv -> WkT/WvT bf16 (WT[c][k] = W[k][c])
// ---------------------------------------------------------------------------
__global__ __launch_bounds__(256) void transpose_w_kernel(
    const float* __restrict__ Wk, const float* __restrict__ Wv,
    unsigned short* __restrict__ WkT, unsigned short* __restrict__ WvT) {
  const float* W = blockIdx.y ? Wv : Wk;
  unsigned short* WT = blockIdx.y ? WvT : WkT;
  const int c = blockIdx.x, k = threadIdx.x;
  WT[c * H + k] = f2bf(W[(size_t)k * H + c]);
}

// ---------------------------------------------------------------------------
// qproj: q = relu(enc@Wq+bq)/16, 4 rows per block -> qb (fp32)
// ---------------------------------------------------------------------------
__global__ __launch_bounds__(256) void qproj_kernel(
    const float* __restrict__ enc, const float* __restrict__ Wq,
    const float* __restrict__ bq, float* __restrict__ qout) {
  __shared__ float xs[4][H];
  const int t = threadIdx.x;
  const int row0 = blockIdx.x * 4;
  {
    float4 v = *(const float4*)(enc + (size_t)(row0 + (t >> 6)) * H + (t & 63) * 4);
    *(float4*)(&xs[t >> 6][(t & 63) * 4]) = v;
  }
  __syncthreads();
  float acc[4] = {0.f, 0.f, 0.f, 0.f};
#pragma unroll 4
  for (int k = 0; k < H; ++k) {
    const float w = Wq[(size_t)k * H + t];
#pragma unroll
    for (int r = 0; r < 4; ++r) acc[r] = fmaf(xs[r][k], w, acc[r]);
  }
  const float b = bq[t];
#pragma unroll
  for (int r = 0; r < 4; ++r)
    qout[(size_t)(row0 + r) * H + t] = fmaxf(acc[r] + b, 0.f) * 0.0625f;
}

// ---------------------------------------------------------------------------
// kvproj: K/V = relu(soc@W+b) via bf16 MFMA. 128x128 tile, BK=64.
// LDS staged with global_load_lds(16B), XOR-swizzled via pre-swizzled source.
// grid = (rows/128, 2 coltiles, 2 outputs)
// ---------------------------------------------------------------------------
__global__ __launch_bounds__(256) void kvproj_kernel(
    const unsigned short* __restrict__ socb,
    const unsigned short* __restrict__ WkT,
    const unsigned short* __restrict__ WvT,
    const float* __restrict__ bk, const float* __restrict__ bv,
    unsigned short* __restrict__ kout, unsigned short* __restrict__ vout) {
  __shared__ __align__(16) unsigned short As[128 * 64];
  __shared__ __align__(16) unsigned short Bs[128 * 64];
  const int t = threadIdx.x;
  const int lane = t & 63, wid = t >> 6;
  const int brow = blockIdx.x * 128;
  const int col0 = blockIdx.y * 128;
  const unsigned short* bT = blockIdx.z ? WvT : WkT;
  const float* bias = blockIdx.z ? bv : bk;
  unsigned short* outp = blockIdx.z ? vout : kout;

  const int srow = t >> 3;   // 0..31 within a 32-row chunk
  const int slin = t & 7;    // linear 16B slot within row

  f32x4 acc[4][4];
#pragma unroll
  for (int m = 0; m < 4; ++m)
#pragma unroll
    for (int n = 0; n < 4; ++n) acc[m][n] = (f32x4)0.f;

  const int wr = wid >> 1, wc = wid & 1;

  for (int k0 = 0; k0 < H; k0 += 64) {
#pragma unroll
    for (int c = 0; c < 4; ++c) {
      const int row = c * 32 + srow;
      const int ssrc = slin ^ (row & 7);  // pre-swizzled source slot
      gload16(socb + (size_t)(brow + row) * H + k0 + ssrc * 8,
              (char*)As + c * 4096 + wid * 1024);
      gload16(bT + (size_t)(col0 + row) * H + k0 + ssrc * 8,
              (char*)Bs + c * 4096 + wid * 1024);
    }
    asm volatile("s_waitcnt vmcnt(0)" ::: "memory");
    __syncthreads();
#pragma unroll
    for (int kk = 0; kk < 2; ++kk) {
      short8 af[4], bfr[4];
#pragma unroll
      for (int m = 0; m < 4; ++m) {
        const int ar = wr * 64 + m * 16 + (lane & 15);
        const int sl = (kk * 4 + (lane >> 4)) ^ (ar & 7);
        af[m] = *(const short8*)((const char*)As + ar * 128 + sl * 16);
      }
#pragma unroll
      for (int n = 0; n < 4; ++n) {
        const int br = wc * 64 + n * 16 + (lane & 15);
        const int sl = (kk * 4 + (lane >> 4)) ^ (br & 7);
        bfr[n] = *(const short8*)((const char*)Bs + br * 128 + sl * 16);
      }
#pragma unroll
      for (int m = 0; m < 4; ++m)
#pragma unroll
        for (int n = 0; n < 4; ++n)
          acc[m][n] = __builtin_amdgcn_mfma_f32_16x16x32_bf16(
              af[m], bfr[n], acc[m][n], 0, 0, 0);
    }
    __syncthreads();
  }

  // epilogue: bias + relu -> bf16
  float bn[4];
#pragma unroll
  for (int n = 0; n < 4; ++n) bn[n] = bias[col0 + wc * 64 + n * 16 + (lane & 15)];
#pragma unroll
  for (int m = 0; m < 4; ++m)
#pragma unroll
    for (int n = 0; n < 4; ++n)
#pragma unroll
      for (int r = 0; r < 4; ++r) {
        const float val = fmaxf(acc[m][n][r] + bn[n], 0.f);
        const int row = brow + wr * 64 + m * 16 + (lane >> 4) * 4 + r;
        const int col = col0 + wc * 64 + n * 16 + (lane & 15);
        outp[(size_t)row * H + col] = f2bf(val);
      }
}

// ---------------------------------------------------------------------------
// attn: per-sample sliced attention; q fp32, k/v bf16
// ---------------------------------------------------------------------------
__global__ __launch_bounds__(256) void attn_kernel(
    const float* __restrict__ qb, const unsigned short* __restrict__ kb,
    const unsigned short* __restrict__ vb, const int* __restrict__ starts,
    const int* __restrict__ ends, float* __restrict__ out) {
  __shared__ float sc[MAXN];
  const int row = blockIdx.x, t = threadIdx.x;
  const int lane = t & 63, wave = t >> 6;
  const int start = starts[row];
  const int len = ends[row] - start;  // 1..64

  const float4 qv = *(const float4*)(qb + (size_t)row * H + lane * 4);

  for (int j = wave; j < len; j += 4) {
    const ushort4 k4 = *(const ushort4*)(kb + (size_t)(start + j) * H + lane * 4);
    float s = qv.x * b2f(k4.x) + qv.y * b2f(k4.y) +
              qv.z * b2f(k4.z) + qv.w * b2f(k4.w);
#pragma unroll
    for (int off = 32; off; off >>= 1) s += __shfl_down(s, off, 64);
    if (lane == 0) sc[j] = s;
  }
  __syncthreads();

  if (t < 64) {
    const float x = (t < len) ? sc[t] : -INFINITY;
    float m = x;
#pragma unroll
    for (int off = 32; off; off >>= 1) m = fmaxf(m, __shfl_xor(m, off, 64));
    const float p = (t < len) ? __expf(x - m) : 0.f;
    float ssum = p;
#pragma unroll
    for (int off = 32; off; off >>= 1) ssum += __shfl_xor(ssum, off, 64);
    sc[t] = p / ssum;
  }
  __syncthreads();

  float acc = 0.f;
  for (int j = 0; j < len; ++j)
    acc = fmaf(sc[j], b2f(vb[(size_t)(start + j) * H + t]), acc);
  out[(size_t)row * H + t] = acc;
}

// ---------------------------------------------------------------------------
extern "C" void kernel_launch(void* const* d_in, const int* in_sizes, int n_in,
                              void* d_out, int out_size, void* d_ws,
                              size_t ws_size, hipStream_t stream) {
  (void)in_sizes; (void)n_in; (void)out_size; (void)ws_size;
  const float* enc = (const float*)d_in[0];
  const float* soc = (const float*)d_in[1];
  const int* starts = (const int*)d_in[2];
  const int* ends = (const int*)d_in[3];
  const float* Wq = (const float*)d_in[4];
  const float* bq = (const float*)d_in[5];
  const float* Wk = (const float*)d_in[6];
  const float* bk = (const float*)d_in[7];
  const float* Wv = (const float*)d_in[8];
  const float* bv = (const float*)d_in[9];
  float* out = (float*)d_out;

  unsigned short* kb = (unsigned short*)d_ws;            // 16 MB
  unsigned short* vb = kb + (size_t)NPOOL * H;           // 16 MB
  unsigned short* socb = vb + (size_t)NPOOL * H;         // 16 MB
  unsigned short* WkT = socb + (size_t)NPOOL * H;        // 128 KB
  unsigned short* WvT = WkT + H * H;                     // 128 KB
  float* qbuf = (float*)(WvT + H * H);                   // 1 MB

  convert_soc_kernel<<<NPOOL * H / (256 * 8), 256, 0, stream>>>(soc, socb);
  transpose_w_kernel<<<dim3(H, 2), 256, 0, stream>>>(Wk, Wv, WkT, WvT);
  qproj_kernel<<<BQ / 4, 256, 0, stream>>>(enc, Wq, bq, qbuf);
  kvproj_kernel<<<dim3(NPOOL / 128, 2, 2), 256, 0, stream>>>(
      socb, WkT, WvT, bk, bv, kb, vb);
  attn_kernel<<<BQ, 256, 0, stream>>>(qbuf, kb, vb, starts, ends, out);
}